// Round 5
// baseline (409.029 us; speedup 1.0000x reference)
//
#include <hip/hip_runtime.h>
#include <hip/hip_bf16.h>
#include <float.h>

#define NPT    4096
#define EMB    512
#define NH     8
#define HD     64
#define KSPLIT 32     // score k-range split: KRANGE = 128

typedef __attribute__((ext_vector_type(8))) short bf16x8;
typedef __attribute__((ext_vector_type(4))) float f32x4;

// ---------------------------------------------------------------------------
// 1) pack adj (int32 0/1, [N][N]) into bitmask [N][N/32]
// ---------------------------------------------------------------------------
__global__ __launch_bounds__(256) void pack_adj_kernel(const int* __restrict__ adj,
                                                       unsigned* __restrict__ bits) {
    int gid = blockIdx.x * 256 + threadIdx.x;
    int q = gid >> 7;
    int w = gid & 127;
    const int4* p = (const int4*)(adj + (size_t)q * NPT + w * 32);
    unsigned m = 0;
#pragma unroll
    for (int i = 0; i < 8; ++i) {
        int4 v = p[i];
        m |= (v.x != 0 ? 1u : 0u) << (i * 4 + 0);
        m |= (v.y != 0 ? 1u : 0u) << (i * 4 + 1);
        m |= (v.z != 0 ? 1u : 0u) << (i * 4 + 2);
        m |= (v.w != 0 ? 1u : 0u) << (i * 4 + 3);
    }
    bits[gid] = m;
}

// ---------------------------------------------------------------------------
// helper: exact 3-way bf16 split of an f32 (hi+mid+lo covers all 24 bits)
// ---------------------------------------------------------------------------
__device__ __forceinline__ void split3(float a, unsigned short& h,
                                       unsigned short& m, unsigned short& l) {
    __hip_bfloat16 bh = __float2bfloat16(a);
    float fh = __bfloat162float(bh);
    float r1 = a - fh;
    __hip_bfloat16 bm = __float2bfloat16(r1);
    float fm = __bfloat162float(bm);
    float r2 = r1 - fm;
    __hip_bfloat16 bl = __float2bfloat16(r2);
    h = *reinterpret_cast<unsigned short*>(&bh);
    m = *reinterpret_cast<unsigned short*>(&bm);
    l = *reinterpret_cast<unsigned short*>(&bl);
}

// ---------------------------------------------------------------------------
// 2) elementwise: split x, WQ, WK, WV into 3 bf16 planes each (K-major kept)
//    y=0 -> x (2048 blocks of float4), y=1..3 -> W (256 blocks)
// ---------------------------------------------------------------------------
__global__ __launch_bounds__(256) void split_planes(const float* __restrict__ x,
                                                    const float* __restrict__ wq,
                                                    const float* __restrict__ wk,
                                                    const float* __restrict__ wv,
                                                    unsigned short* __restrict__ xs,
                                                    unsigned short* __restrict__ wqs,
                                                    unsigned short* __restrict__ wks,
                                                    unsigned short* __restrict__ wvs) {
    const float* src; unsigned short* dst; size_t n4, PL;
    int y = blockIdx.y;
    if (y == 0)      { src = x;  dst = xs;  PL = (size_t)NPT * EMB; }
    else if (y == 1) { src = wq; dst = wqs; PL = (size_t)EMB * EMB; }
    else if (y == 2) { src = wk; dst = wks; PL = (size_t)EMB * EMB; }
    else             { src = wv; dst = wvs; PL = (size_t)EMB * EMB; }
    n4 = PL / 4;
    size_t i = (size_t)blockIdx.x * 256 + threadIdx.x;
    if (i >= n4) return;
    float4 v = ((const float4*)src)[i];
    ushort4 h, m, l;
    split3(v.x, h.x, m.x, l.x);
    split3(v.y, h.y, m.y, l.y);
    split3(v.z, h.z, m.z, l.z);
    split3(v.w, h.w, m.w, l.w);
    ((ushort4*)dst)[i]            = h;
    ((ushort4*)(dst + PL))[i]     = m;
    ((ushort4*)(dst + 2 * PL))[i] = l;
}

// ---------------------------------------------------------------------------
// 3) projections via split-bf16 MFMA (6 plane-products -> f32-exact to ~1e-6).
//    D[e][n] = sum_k W[e][k] x[n][k];  A = W (M=e), B = x (N=n).
//    Block: 64e x 128n, 4 waves (wave w: n-range w*32). No LDS, no barriers.
//    z=0 -> Q3 planes [3][NH][NPT][HD]; z=1 -> K3; z=2 -> V f32 [n][e].
// ---------------------------------------------------------------------------
__global__ __launch_bounds__(256) void gemm_mfma(const unsigned short* __restrict__ xs,
                                                 const unsigned short* __restrict__ wqs,
                                                 const unsigned short* __restrict__ wks,
                                                 const unsigned short* __restrict__ wvs,
                                                 unsigned short* __restrict__ Q3,
                                                 unsigned short* __restrict__ K3,
                                                 float* __restrict__ V) {
    const int z = blockIdx.z;
    const unsigned short* W3 = (z == 0) ? wqs : (z == 1) ? wks : wvs;
    unsigned short* O3 = (z == 0) ? Q3 : K3;
    const size_t XPL = (size_t)NPT * EMB;     // x plane stride
    const size_t WPL = (size_t)EMB * EMB;     // W plane stride
    const size_t OPL = (size_t)NH * NPT * HD; // out plane stride

    const int nb = blockIdx.x * 128;
    const int eb = blockIdx.y * 64;
    const int tid = threadIdx.x;
    const int wv = tid >> 6, lane = tid & 63;
    const int m = lane & 15, quad = lane >> 4;
    const int n0 = nb + wv * 32;

    f32x4 acc[4][2];    // [mt: e-tile][nt: n-tile]
#pragma unroll
    for (int mt = 0; mt < 4; ++mt)
#pragma unroll
        for (int nt = 0; nt < 2; ++nt) acc[mt][nt] = (f32x4){0.f, 0.f, 0.f, 0.f};

#pragma unroll 2
    for (int kc = 0; kc < 16; ++kc) {
        const int k0 = kc * 32;
        bf16x8 af[4][3], bf[2][3];
#pragma unroll
        for (int mt = 0; mt < 4; ++mt)
#pragma unroll
            for (int p = 0; p < 3; ++p)
                af[mt][p] = *(const bf16x8*)(W3 + (size_t)p * WPL
                    + (size_t)(eb + mt * 16 + m) * EMB + k0 + quad * 8);
#pragma unroll
        for (int nt = 0; nt < 2; ++nt)
#pragma unroll
            for (int p = 0; p < 3; ++p)
                bf[nt][p] = *(const bf16x8*)(xs + (size_t)p * XPL
                    + (size_t)(n0 + nt * 16 + m) * EMB + k0 + quad * 8);
#pragma unroll
        for (int mt = 0; mt < 4; ++mt)
#pragma unroll
            for (int nt = 0; nt < 2; ++nt) {
                f32x4 a = acc[mt][nt];
                a = __builtin_amdgcn_mfma_f32_16x16x32_bf16(af[mt][0], bf[nt][0], a, 0, 0, 0);
                a = __builtin_amdgcn_mfma_f32_16x16x32_bf16(af[mt][0], bf[nt][1], a, 0, 0, 0);
                a = __builtin_amdgcn_mfma_f32_16x16x32_bf16(af[mt][1], bf[nt][0], a, 0, 0, 0);
                a = __builtin_amdgcn_mfma_f32_16x16x32_bf16(af[mt][1], bf[nt][1], a, 0, 0, 0);
                a = __builtin_amdgcn_mfma_f32_16x16x32_bf16(af[mt][0], bf[nt][2], a, 0, 0, 0);
                a = __builtin_amdgcn_mfma_f32_16x16x32_bf16(af[mt][2], bf[nt][0], a, 0, 0, 0);
                acc[mt][nt] = a;
            }
    }

    // C/D layout: col(lane&15) = n, row(quad*4+r) = e -> regs are consecutive d
#pragma unroll
    for (int mt = 0; mt < 4; ++mt)
#pragma unroll
        for (int nt = 0; nt < 2; ++nt) {
            const int n = n0 + nt * 16 + m;
            const int d0 = mt * 16 + quad * 4;       // e = eb + d0 (+r)
            f32x4 a = acc[mt][nt];
            if (z == 2) {
                *(f32x4*)(V + (size_t)n * EMB + eb + d0) = a;
            } else {
                const int h = eb >> 6;
                ushort4 ph, pm, pl;
                split3(a[0], ph.x, pm.x, pl.x);
                split3(a[1], ph.y, pm.y, pl.y);
                split3(a[2], ph.z, pm.z, pl.z);
                split3(a[3], ph.w, pm.w, pl.w);
                size_t base = ((size_t)h * NPT + n) * HD + d0;
                *(ushort4*)(O3 + base)           = ph;
                *(ushort4*)(O3 + OPL + base)     = pm;
                *(ushort4*)(O3 + 2 * OPL + base) = pl;
            }
        }
}

// ---------------------------------------------------------------------------
// 4) masked argmax via bf16x3 MFMA, fragments direct from global (no LDS, no
//    barriers). A = K (m=k), B = Q (n=q). Wave: 64q x 128k, 4 waves/block.
// ---------------------------------------------------------------------------
__global__ __launch_bounds__(256, 2) void score_mfma(const unsigned short* __restrict__ Q3,
                                                     const unsigned short* __restrict__ K3,
                                                     const unsigned* __restrict__ bits,
                                                     float* __restrict__ pval,
                                                     int* __restrict__ pidx) {
    const int ks  = blockIdx.x;              // 0..KSPLIT-1, KRANGE=128
    const int qb  = blockIdx.y * 256;
    const int tid = threadIdx.x;
    const int wv  = tid >> 6;
    const int lane = tid & 63;
    const int m    = lane & 15;
    const int quad = lane >> 4;
    const size_t PL = (size_t)NH * NPT * HD;
    const int kq = qb + wv * 64;

    for (int h = 0; h < NH; ++h) {
        // persistent Q fragments (B-layout: n=lane&15, k=quad*8+j)
        bf16x8 qf[4][2][3];
#pragma unroll
        for (int nt = 0; nt < 4; ++nt)
#pragma unroll
            for (int dc = 0; dc < 2; ++dc)
#pragma unroll
                for (int p = 0; p < 3; ++p)
                    qf[nt][dc][p] = *(const bf16x8*)(Q3 + (size_t)p * PL
                        + ((size_t)h * NPT + kq + nt * 16 + m) * HD + dc * 32 + quad * 8);

        float bestv[4]; int besti[4];
#pragma unroll
        for (int nt = 0; nt < 4; ++nt) { bestv[nt] = -FLT_MAX; besti[nt] = 0; }

#pragma unroll 1
        for (int kst = 0; kst < 4; ++kst) {  // 32 k per step
            bf16x8 kf[2][2][3];              // A-layout: m=lane&15 -> k row
#pragma unroll
            for (int mt = 0; mt < 2; ++mt)
#pragma unroll
                for (int dc = 0; dc < 2; ++dc)
#pragma unroll
                    for (int p = 0; p < 3; ++p)
                        kf[mt][dc][p] = *(const bf16x8*)(K3 + (size_t)p * PL
                            + ((size_t)h * NPT + ks * 128 + kst * 32 + mt * 16 + m) * HD
                            + dc * 32 + quad * 8);

            f32x4 acc[2][4];
#pragma unroll
            for (int mt = 0; mt < 2; ++mt)
#pragma unroll
                for (int nt = 0; nt < 4; ++nt) {
                    f32x4 a = {0.f, 0.f, 0.f, 0.f};
#pragma unroll
                    for (int dc = 0; dc < 2; ++dc) {
                        a = __builtin_amdgcn_mfma_f32_16x16x32_bf16(kf[mt][dc][0], qf[nt][dc][0], a, 0, 0, 0);
                        a = __builtin_amdgcn_mfma_f32_16x16x32_bf16(kf[mt][dc][0], qf[nt][dc][1], a, 0, 0, 0);
                        a = __builtin_amdgcn_mfma_f32_16x16x32_bf16(kf[mt][dc][1], qf[nt][dc][0], a, 0, 0, 0);
                        a = __builtin_amdgcn_mfma_f32_16x16x32_bf16(kf[mt][dc][1], qf[nt][dc][1], a, 0, 0, 0);
                        a = __builtin_amdgcn_mfma_f32_16x16x32_bf16(kf[mt][dc][0], qf[nt][dc][2], a, 0, 0, 0);
                        a = __builtin_amdgcn_mfma_f32_16x16x32_bf16(kf[mt][dc][2], qf[nt][dc][0], a, 0, 0, 0);
                    }
                    acc[mt][nt] = a;
                }

            // epilogue: C col=lane&15 -> q; row=quad*4+reg -> k
            const int kbase = ks * 128 + kst * 32;
#pragma unroll
            for (int nt = 0; nt < 4; ++nt) {
                int q = kq + nt * 16 + m;
                unsigned w = bits[(size_t)q * (NPT / 32) + (kbase >> 5)];
#pragma unroll
                for (int mt = 0; mt < 2; ++mt) {
                    int k0 = mt * 16 + quad * 4;
                    f32x4 a = acc[mt][nt];
#pragma unroll
                    for (int r = 0; r < 4; ++r) {
                        if ((w >> (k0 + r)) & 1u) {
                            float s = a[r];
                            if (s > bestv[nt]) { bestv[nt] = s; besti[nt] = kbase + k0 + r; }
                        }
                    }
                }
            }
        }

        // reduce across quad groups (lanes sharing lane&15); smaller idx on tie
#pragma unroll
        for (int nt = 0; nt < 4; ++nt) {
            float v = bestv[nt]; int bi = besti[nt];
#pragma unroll
            for (int off = 16; off < 64; off <<= 1) {
                float ov = __shfl_xor(v, off);
                int   oi = __shfl_xor(bi, off);
                if (ov > v || (ov == v && oi < bi)) { v = ov; bi = oi; }
            }
            if (quad == 0) {
                size_t o = ((size_t)h * KSPLIT + ks) * NPT + kq + nt * 16 + m;
                pval[o] = v; pidx[o] = bi;
            }
        }
    }
}

// ---------------------------------------------------------------------------
// 5) reduce k-split partials, gather winner V row * (1/NH)
// ---------------------------------------------------------------------------
__global__ __launch_bounds__(128) void gather_out(const float* __restrict__ V,
                                                  const float* __restrict__ pval,
                                                  const int* __restrict__ pidx,
                                                  float* __restrict__ out) {
    const int q = blockIdx.x;
    const int tid = threadIdx.x;
    __shared__ int widx[NH];
    if (tid < NH) {
        float bv = -FLT_MAX; int bi = 0;
        for (int ks = 0; ks < KSPLIT; ++ks) {
            size_t off = ((size_t)tid * KSPLIT + ks) * NPT + q;
            float v = pval[off];
            if (v > bv) { bv = v; bi = pidx[off]; }
        }
        widx[tid] = bi;
    }
    __syncthreads();
    const int h = tid >> 4;
    const int d4 = (tid & 15) * 4;
    const int k = widx[h];
    float4 v = *(const float4*)(V + (size_t)k * EMB + h * HD + d4);
    v.x *= 0.125f; v.y *= 0.125f; v.z *= 0.125f; v.w *= 0.125f;
    *(float4*)(out + (size_t)q * EMB + h * HD + d4) = v;
}

// ---------------------------------------------------------------------------
extern "C" void kernel_launch(void* const* d_in, const int* in_sizes, int n_in,
                              void* d_out, int out_size, void* d_ws, size_t ws_size,
                              hipStream_t stream) {
    const float* x   = (const float*)d_in[0];
    const int*   adj = (const int*)d_in[1];
    const float* WQ  = (const float*)d_in[2];
    const float* WK  = (const float*)d_in[3];
    const float* WV  = (const float*)d_in[4];
    // we/be are dead: energy is constant along k -> argmax unchanged.
    float* out = (float*)d_out;

    char* ws = (char*)d_ws;
    const size_t MB = 1u << 20;
    unsigned short* xs   = (unsigned short*)(ws);                      // 12 MB (dead after gemm)
    unsigned short* wqs  = (unsigned short*)(ws + 12 * MB);            // 1.5 MB
    unsigned short* wks  = (unsigned short*)(ws + 13 * MB + 512 * 1024);
    unsigned short* wvs  = (unsigned short*)(ws + 15 * MB);
    unsigned short* Q3   = (unsigned short*)(ws + 17 * MB);            // 12 MB [3][8][4096][64]
    unsigned short* K3   = (unsigned short*)(ws + 29 * MB);            // 12 MB
    float*          V    = (float*)(ws + 41 * MB);                     // 8 MB [4096][512]
    unsigned*       bits = (unsigned*)(ws + 49 * MB);                  // 2 MB
    float*          pval = (float*)(ws);                               // 4 MB, aliases dead xs
    int*            pidx = (int*)(ws + 4 * MB);                        // 4 MB, aliases dead xs

    pack_adj_kernel<<<dim3(NPT * 128 / 256), dim3(256), 0, stream>>>(adj, bits);
    split_planes<<<dim3(2048, 4), dim3(256), 0, stream>>>(x, WQ, WK, WV, xs, wqs, wks, wvs);
    gemm_mfma<<<dim3(NPT / 128, EMB / 64, 3), dim3(256), 0, stream>>>(xs, wqs, wks, wvs, Q3, K3, V);
    score_mfma<<<dim3(KSPLIT, NPT / 256), dim3(256), 0, stream>>>(Q3, K3, bits, pval, pidx);
    gather_out<<<dim3(NPT), dim3(128), 0, stream>>>(V, pval, pidx, out);
}